// Round 1
// baseline (305.765 us; speedup 1.0000x reference)
//
#include <hip/hip_runtime.h>

#define B_  32
#define S_  1024
#define H_  1024
#define V_  50257

typedef __attribute__((ext_vector_type(8))) short bf16x8;
typedef __attribute__((ext_vector_type(4))) float f32x4;
typedef __attribute__((ext_vector_type(8))) unsigned short u16x8;

__device__ __forceinline__ unsigned short f2b(float f) {
  union { float f; unsigned u; } v; v.f = f;
  unsigned r = 0x7FFFu + ((v.u >> 16) & 1u);
  return (unsigned short)((v.u + r) >> 16);
}
__device__ __forceinline__ float b2f(unsigned short h) {
  union { unsigned u; float f; } v; v.u = ((unsigned)h) << 16;
  return v.f;
}

// CK-style addrspace cast via integer round-trip (generic LDS ptr low 32 bits == LDS offset)
__device__ __forceinline__ void async16(void* lds, const void* g) {
  typedef __attribute__((address_space(3))) void as3_void;
  typedef __attribute__((address_space(1))) void as1_void;
  as3_void* l = (as3_void*)(unsigned)(unsigned long long)lds;
  const as1_void* s = (const as1_void*)(unsigned long long)g;
  __builtin_amdgcn_global_load_lds(s, l, 16, 0, 0);
}

// ---------- converts ----------
__global__ void conv_f32_bf16(const float* __restrict__ src, unsigned short* __restrict__ dst) {
  size_t i = ((size_t)blockIdx.x * 256 + threadIdx.x) * 8;
  float4 v0 = *(const float4*)(src + i);
  float4 v1 = *(const float4*)(src + i + 4);
  u16x8 o;
  o[0]=f2b(v0.x); o[1]=f2b(v0.y); o[2]=f2b(v0.z); o[3]=f2b(v0.w);
  o[4]=f2b(v1.x); o[5]=f2b(v1.y); o[6]=f2b(v1.z); o[7]=f2b(v1.w);
  *(u16x8*)(dst + i) = o;
}

// W_a1[:, :H] (enc half) -> bf16 [H][H]
__global__ void conv_wa1(const float* __restrict__ wa1, unsigned short* __restrict__ dst) {
  size_t i = ((size_t)blockIdx.x * 256 + threadIdx.x) * 8;  // over H_*H_
  int h = (int)(i >> 10), k = (int)(i & 1023);
  const float* s = wa1 + (size_t)h * 2048 + k;
  float4 v0 = *(const float4*)(s);
  float4 v1 = *(const float4*)(s + 4);
  u16x8 o;
  o[0]=f2b(v0.x); o[1]=f2b(v0.y); o[2]=f2b(v0.z); o[3]=f2b(v0.w);
  o[4]=f2b(v1.x); o[5]=f2b(v1.y); o[6]=f2b(v1.z); o[7]=f2b(v1.w);
  *(u16x8*)(dst + i) = o;
}

// part2[b][h] = b_a1[h] + sum_k h_prev[b][k] * W_a1[h][H+k]   (f32, exact-ish)
__global__ void part2_kernel(const float* __restrict__ wa1, const float* __restrict__ hidden,
                             const float* __restrict__ b_a1, float* __restrict__ part2) {
  int h = blockIdx.x;
  __shared__ float wrow[H_];
  for (int i = threadIdx.x; i < H_; i += 256) wrow[i] = wa1[(size_t)h * 2048 + 1024 + i];
  __syncthreads();
  int wave = threadIdx.x >> 6, lane = threadIdx.x & 63;
  float bias = b_a1[h];
  for (int bb = 0; bb < 8; ++bb) {
    int b = wave * 8 + bb;
    float acc = 0.f;
    for (int k = lane; k < H_; k += 64) acc += wrow[k] * hidden[b * H_ + k];
    #pragma unroll
    for (int off = 32; off; off >>= 1) acc += __shfl_xor(acc, off);
    if (lane == 0) part2[b * H_ + h] = acc + bias;
  }
}

// ---------- big scores GEMM (m97-style 128x128, BK=32) ----------
// partials[m][nb] = sum over 64-col group nb of W_a2[n]*tanh(acc[m][n] + part2[b][n])
__global__ __launch_bounds__(256) void scores_gemm(
    const unsigned short* __restrict__ A,   // enc_bf [32768][1024]
    const unsigned short* __restrict__ Bm,  // wa1_bf [1024][1024]
    const float* __restrict__ part2,        // [32][1024]
    const float* __restrict__ wa2,          // [1024]
    float* __restrict__ partials)           // [32768][16]
{
  constexpr int K = H_;
  __shared__ __align__(16) unsigned short As[128 * 32];
  __shared__ __align__(16) unsigned short Bs[128 * 32];
  const int bm = blockIdx.x, bn = blockIdx.y;
  const int tid = threadIdx.x;
  const int wave = tid >> 6, lane = tid & 63;
  const int wr = wave >> 1, wc = wave & 1;
  const int l15 = lane & 15, l16 = lane >> 4;
  const int srow = lane >> 2, sseg = lane & 3;

  f32x4 acc[4][4];
  #pragma unroll
  for (int mi = 0; mi < 4; ++mi)
    #pragma unroll
    for (int ni = 0; ni < 4; ++ni) acc[mi][ni] = (f32x4){0.f, 0.f, 0.f, 0.f};

  for (int kt = 0; kt < K; kt += 32) {
    #pragma unroll
    for (int i = 0; i < 2; ++i) {
      int c = wave * 2 + i;
      int row = c * 16 + srow;
      async16(&As[c * 512], A  + (size_t)(bm * 128 + row) * K + kt + sseg * 8);
      async16(&Bs[c * 512], Bm + (size_t)(bn * 128 + row) * K + kt + sseg * 8);
    }
    asm volatile("s_waitcnt vmcnt(0)" ::: "memory");
    __syncthreads();
    bf16x8 af[4], bfr[4];
    #pragma unroll
    for (int mi = 0; mi < 4; ++mi)
      af[mi] = *(const bf16x8*)&As[(wr * 64 + mi * 16 + l15) * 32 + l16 * 8];
    #pragma unroll
    for (int ni = 0; ni < 4; ++ni)
      bfr[ni] = *(const bf16x8*)&Bs[(wc * 64 + ni * 16 + l15) * 32 + l16 * 8];
    #pragma unroll
    for (int mi = 0; mi < 4; ++mi)
      #pragma unroll
      for (int ni = 0; ni < 4; ++ni)
        acc[mi][ni] = __builtin_amdgcn_mfma_f32_16x16x32_bf16(af[mi], bfr[ni], acc[mi][ni], 0, 0, 0);
    __syncthreads();
  }

  const int b = bm >> 3;  // 128 rows per block, 1024 rows per batch
  float w2[4], p2[4];
  #pragma unroll
  for (int ni = 0; ni < 4; ++ni) {
    int col = bn * 128 + wc * 64 + ni * 16 + l15;
    w2[ni] = wa2[col];
    p2[ni] = part2[b * H_ + col];
  }
  #pragma unroll
  for (int mi = 0; mi < 4; ++mi) {
    #pragma unroll
    for (int r = 0; r < 4; ++r) {
      float s = 0.f;
      #pragma unroll
      for (int ni = 0; ni < 4; ++ni)
        s += w2[ni] * tanhf(acc[mi][ni][r] + p2[ni]);
      s += __shfl_xor(s, 1); s += __shfl_xor(s, 2);
      s += __shfl_xor(s, 4); s += __shfl_xor(s, 8);
      if (l15 == 0) {
        int row = bm * 128 + wr * 64 + mi * 16 + l16 * 4 + r;
        partials[(size_t)row * 16 + bn * 2 + wc] = s;
      }
    }
  }
}

// ---------- softmax over S per b ----------
__global__ void softmax_kernel(const float* __restrict__ partials, const float* __restrict__ b_a2,
                               float* __restrict__ attn) {
  int b = blockIdx.x, s = threadIdx.x;       // block 1024
  int lane = s & 63, wid = s >> 6;
  const float4* p = (const float4*)(partials + (size_t)(b * S_ + s) * 16);
  float sc = b_a2[0];
  #pragma unroll
  for (int i = 0; i < 4; ++i) { float4 v = p[i]; sc += v.x + v.y + v.z + v.w; }
  __shared__ float rmax[16], rsum[16];
  float m = sc;
  #pragma unroll
  for (int off = 32; off; off >>= 1) m = fmaxf(m, __shfl_xor(m, off));
  if (lane == 0) rmax[wid] = m;
  __syncthreads();
  float M = rmax[0];
  #pragma unroll
  for (int i = 1; i < 16; ++i) M = fmaxf(M, rmax[i]);
  float e = expf(sc - M);
  float su = e;
  #pragma unroll
  for (int off = 32; off; off >>= 1) su += __shfl_xor(su, off);
  if (lane == 0) rsum[wid] = su;
  __syncthreads();
  float T = 0.f;
  #pragma unroll
  for (int i = 0; i < 16; ++i) T += rsum[i];
  attn[b * S_ + s] = e / T;
}

// ---------- context partials: ctxp[sc][b][h] = sum_{s in chunk} attn[b][s]*enc[b][s][h] ----------
__global__ void ctx_partial_kernel(const unsigned short* __restrict__ encbf,
                                   const float* __restrict__ attn, float* __restrict__ ctxp) {
  int sc = blockIdx.x, b = blockIdx.y, t = threadIdx.x;
  int h4 = t * 4;
  float a0 = 0, a1 = 0, a2 = 0, a3 = 0;
  const unsigned short* base = encbf + (size_t)b * S_ * H_ + h4;
  const float* aw = attn + b * S_ + sc * 128;
  #pragma unroll 4
  for (int i = 0; i < 128; ++i) {
    float w = aw[i];
    ushort4 ev = *(const ushort4*)(base + (size_t)(sc * 128 + i) * H_);
    a0 += w * b2f(ev.x); a1 += w * b2f(ev.y); a2 += w * b2f(ev.z); a3 += w * b2f(ev.w);
  }
  float4 o = {a0, a1, a2, a3};
  *(float4*)(ctxp + (size_t)(sc * B_ + b) * H_ + h4) = o;
}

// ---------- prep: reduce ctx, build ec_bf = [emb_row | ctx], hprev_bf ----------
__global__ void prep_kernel(const float* __restrict__ ctxp, const float* __restrict__ emb,
                            const int* __restrict__ word, const float* __restrict__ hidden,
                            unsigned short* __restrict__ ec_bf, unsigned short* __restrict__ hprev_bf) {
  int b = blockIdx.x;
  int w = word[b];
  for (int h = threadIdx.x; h < H_; h += 256) {
    float c = 0.f;
    #pragma unroll
    for (int sc = 0; sc < 8; ++sc) c += ctxp[(size_t)(sc * B_ + b) * H_ + h];
    ec_bf[b * 2048 + 1024 + h] = f2b(c);
    ec_bf[b * 2048 + h] = f2b(emb[(size_t)w * H_ + h]);
    hprev_bf[b * H_ + h] = f2b(hidden[b * H_ + h]);
  }
}

// ---------- skinny MFMA GEMM: C[32,N] = A_bf[32,K] @ Bf32[N,K]^T ----------
// mode 0: write partial C[(kc*32+m)*N + col];  mode 1: C[m*ldc+col] = acc + bias[col]
__global__ __launch_bounds__(256) void skinny_gemm(
    const unsigned short* __restrict__ A, const float* __restrict__ Bw,
    float* __restrict__ C, const float* __restrict__ bias,
    int N, int K, int KC, int ldc, int mode)
{
  int n0 = blockIdx.x * 64;
  int kc = blockIdx.y;
  int wave = threadIdx.x >> 6, lane = threadIdx.x & 63;
  int l15 = lane & 15, l16 = lane >> 4;
  int col = n0 + wave * 16 + l15;
  int vclamp = col < N ? col : N - 1;
  const unsigned short* a0p = A + l15 * K + l16 * 8;
  const unsigned short* a1p = A + (16 + l15) * K + l16 * 8;
  const float* bp = Bw + (size_t)vclamp * K + l16 * 8;
  f32x4 acc0 = {0.f, 0.f, 0.f, 0.f}, acc1 = {0.f, 0.f, 0.f, 0.f};
  int k0 = kc * KC, k1 = (k0 + KC < K) ? (k0 + KC) : K;
  #pragma unroll 4
  for (int k = k0; k < k1; k += 32) {
    bf16x8 a0 = *(const bf16x8*)(a0p + k);
    bf16x8 a1 = *(const bf16x8*)(a1p + k);
    float4 bv0 = *(const float4*)(bp + k);
    float4 bv1 = *(const float4*)(bp + k + 4);
    bf16x8 bb;
    bb[0] = (short)f2b(bv0.x); bb[1] = (short)f2b(bv0.y);
    bb[2] = (short)f2b(bv0.z); bb[3] = (short)f2b(bv0.w);
    bb[4] = (short)f2b(bv1.x); bb[5] = (short)f2b(bv1.y);
    bb[6] = (short)f2b(bv1.z); bb[7] = (short)f2b(bv1.w);
    acc0 = __builtin_amdgcn_mfma_f32_16x16x32_bf16(a0, bb, acc0, 0, 0, 0);
    acc1 = __builtin_amdgcn_mfma_f32_16x16x32_bf16(a1, bb, acc1, 0, 0, 0);
  }
  if (col < N) {
    #pragma unroll
    for (int r = 0; r < 4; ++r) {
      int m = l16 * 4 + r;
      if (mode == 1) {
        float bv = bias[col];
        C[(size_t)m * ldc + col] = acc0[r] + bv;
        C[(size_t)(16 + m) * ldc + col] = acc1[r] + bv;
      } else {
        C[(size_t)(kc * 32 + m) * N + col] = acc0[r];
        C[(size_t)(kc * 32 + 16 + m) * N + col] = acc1[r];
      }
    }
  }
}

// ---------- x = relu(sum_kc xp + b_c) -> bf16 ----------
__global__ void xfinish_kernel(const float* __restrict__ xp, const float* __restrict__ b_c,
                               unsigned short* __restrict__ x_bf) {
  int i = blockIdx.x * 256 + threadIdx.x;   // 32768
  int b = i >> 10, h = i & 1023;
  float v = b_c[h];
  #pragma unroll
  for (int kc = 0; kc < 8; ++kc) v += xp[(size_t)(kc * B_ + b) * H_ + h];
  x_bf[i] = f2b(v > 0.f ? v : 0.f);
}

// ---------- GRU gates + h_new ----------
__global__ void gates_kernel(const float* __restrict__ gip, const float* __restrict__ ghp,
                             const float* __restrict__ b_ih, const float* __restrict__ b_hh,
                             const float* __restrict__ hidden, float* __restrict__ hnew_out,
                             unsigned short* __restrict__ hr_bf) {
  int i = blockIdx.x * 256 + threadIdx.x;   // 32768
  int b = i >> 10, h = i & 1023;
  float g[6];
  #pragma unroll
  for (int t = 0; t < 3; ++t) {
    int j = h + t * H_;
    float vi = b_ih[j], vh = b_hh[j];
    #pragma unroll
    for (int kc = 0; kc < 4; ++kc) {
      vi += gip[(size_t)(kc * B_ + b) * 3072 + j];
      vh += ghp[(size_t)(kc * B_ + b) * 3072 + j];
    }
    g[t] = vi; g[3 + t] = vh;
  }
  float r = 1.f / (1.f + expf(-(g[0] + g[3])));
  float z = 1.f / (1.f + expf(-(g[1] + g[4])));
  float n = tanhf(g[2] + r * g[5]);
  float hv = (1.f - z) * n + z * hidden[i];
  hnew_out[i] = hv;
  hr_bf[i] = f2b(hv > 0.f ? hv : 0.f);
}

extern "C" void kernel_launch(void* const* d_in, const int* in_sizes, int n_in,
                              void* d_out, int out_size, void* d_ws, size_t ws_size,
                              hipStream_t stream) {
  const int*   word   = (const int*)  d_in[0];
  const float* hidden = (const float*)d_in[1];
  const float* enc    = (const float*)d_in[2];
  const float* emb    = (const float*)d_in[3];
  const float* W_a1   = (const float*)d_in[4];
  const float* b_a1   = (const float*)d_in[5];
  const float* W_a2   = (const float*)d_in[6];
  const float* b_a2   = (const float*)d_in[7];
  const float* W_c    = (const float*)d_in[8];
  const float* b_c    = (const float*)d_in[9];
  const float* W_ih   = (const float*)d_in[10];
  const float* W_hh   = (const float*)d_in[11];
  const float* b_ih   = (const float*)d_in[12];
  const float* b_hh   = (const float*)d_in[13];
  const float* W_fc   = (const float*)d_in[14];
  const float* b_fc   = (const float*)d_in[15];
  float* out = (float*)d_out;

  if (ws_size < 77135872ull) return;  // loud failure (d_out stays poisoned)

  char* ws = (char*)d_ws;
  unsigned short* enc_bf   = (unsigned short*)(ws + 0);
  unsigned short* wa1_bf   = (unsigned short*)(ws + 67108864);
  float*          part2    = (float*)         (ws + 69206016);
  float*          partials = (float*)         (ws + 69337088);
  float*          attn     = (float*)         (ws + 71434240);
  float*          ctxp     = (float*)         (ws + 71565312);
  unsigned short* ec_bf    = (unsigned short*)(ws + 72613888);
  unsigned short* hprev_bf = (unsigned short*)(ws + 72744960);
  float*          xp       = (float*)         (ws + 72810496);
  unsigned short* x_bf     = (unsigned short*)(ws + 73859072);
  float*          gip      = (float*)         (ws + 73924608);
  float*          ghp      = (float*)         (ws + 75497472);
  unsigned short* hr_bf    = (unsigned short*)(ws + 77070336);

  conv_f32_bf16<<<dim3(16384), dim3(256), 0, stream>>>(enc, enc_bf);
  conv_wa1<<<dim3(512), dim3(256), 0, stream>>>(W_a1, wa1_bf);
  part2_kernel<<<dim3(1024), dim3(256), 0, stream>>>(W_a1, hidden, b_a1, part2);
  scores_gemm<<<dim3(256, 8), dim3(256), 0, stream>>>(enc_bf, wa1_bf, part2, W_a2, partials);
  softmax_kernel<<<dim3(32), dim3(1024), 0, stream>>>(partials, b_a2, attn);
  ctx_partial_kernel<<<dim3(8, 32), dim3(256), 0, stream>>>(enc_bf, attn, ctxp);
  prep_kernel<<<dim3(32), dim3(256), 0, stream>>>(ctxp, emb, word, hidden, ec_bf, hprev_bf);
  skinny_gemm<<<dim3(16, 8), dim3(256), 0, stream>>>(ec_bf, W_c, xp, (const float*)nullptr,
                                                     1024, 2048, 256, 0, 0);
  xfinish_kernel<<<dim3(128), dim3(256), 0, stream>>>(xp, b_c, x_bf);
  skinny_gemm<<<dim3(48, 4), dim3(256), 0, stream>>>(x_bf, W_ih, gip, (const float*)nullptr,
                                                     3072, 1024, 256, 0, 0);
  skinny_gemm<<<dim3(48, 4), dim3(256), 0, stream>>>(hprev_bf, W_hh, ghp, (const float*)nullptr,
                                                     3072, 1024, 256, 0, 0);
  gates_kernel<<<dim3(128), dim3(256), 0, stream>>>(gip, ghp, b_ih, b_hh, hidden,
                                                    out + (size_t)B_ * V_, hr_bf);
  skinny_gemm<<<dim3(786, 1), dim3(256), 0, stream>>>(hr_bf, W_fc, out, b_fc,
                                                      V_, 1024, 1024, V_, 1);
}

// Round 2
// 291.305 us; speedup vs baseline: 1.0496x; 1.0496x over previous
//
#include <hip/hip_runtime.h>

#define B_  32
#define S_  1024
#define H_  1024
#define V_  50257

typedef __attribute__((ext_vector_type(8))) short bf16x8;
typedef __attribute__((ext_vector_type(4))) float f32x4;
typedef __attribute__((ext_vector_type(8))) unsigned short u16x8;

__device__ __forceinline__ unsigned short f2b(float f) {
  union { float f; unsigned u; } v; v.f = f;
  unsigned r = 0x7FFFu + ((v.u >> 16) & 1u);
  return (unsigned short)((v.u + r) >> 16);
}
__device__ __forceinline__ float b2f(unsigned short h) {
  union { unsigned u; float f; } v; v.u = ((unsigned)h) << 16;
  return v.f;
}

__device__ __forceinline__ void async16(void* lds, const void* g) {
  typedef __attribute__((address_space(3))) void as3_void;
  typedef __attribute__((address_space(1))) void as1_void;
  as3_void* l = (as3_void*)(unsigned)(unsigned long long)lds;
  const as1_void* s = (const as1_void*)(unsigned long long)g;
  __builtin_amdgcn_global_load_lds(s, l, 16, 0, 0);
}

// ---------- converts ----------
__global__ void conv_f32_bf16(const float* __restrict__ src, unsigned short* __restrict__ dst) {
  size_t i = ((size_t)blockIdx.x * 256 + threadIdx.x) * 8;
  float4 v0 = *(const float4*)(src + i);
  float4 v1 = *(const float4*)(src + i + 4);
  u16x8 o;
  o[0]=f2b(v0.x); o[1]=f2b(v0.y); o[2]=f2b(v0.z); o[3]=f2b(v0.w);
  o[4]=f2b(v1.x); o[5]=f2b(v1.y); o[6]=f2b(v1.z); o[7]=f2b(v1.w);
  *(u16x8*)(dst + i) = o;
}

__global__ void conv_wa1(const float* __restrict__ wa1, unsigned short* __restrict__ dst) {
  size_t i = ((size_t)blockIdx.x * 256 + threadIdx.x) * 8;  // over H_*H_
  int h = (int)(i >> 10), k = (int)(i & 1023);
  const float* s = wa1 + (size_t)h * 2048 + k;
  float4 v0 = *(const float4*)(s);
  float4 v1 = *(const float4*)(s + 4);
  u16x8 o;
  o[0]=f2b(v0.x); o[1]=f2b(v0.y); o[2]=f2b(v0.z); o[3]=f2b(v0.w);
  o[4]=f2b(v1.x); o[5]=f2b(v1.y); o[6]=f2b(v1.z); o[7]=f2b(v1.w);
  *(u16x8*)(dst + i) = o;
}

// part2[b][h] = b_a1[h] + sum_k h_prev[b][k] * W_a1[h][H+k]
__global__ void part2_kernel(const float* __restrict__ wa1, const float* __restrict__ hidden,
                             const float* __restrict__ b_a1, float* __restrict__ part2) {
  int h = blockIdx.x;
  __shared__ float wrow[H_];
  for (int i = threadIdx.x; i < H_; i += 256) wrow[i] = wa1[(size_t)h * 2048 + 1024 + i];
  __syncthreads();
  int wave = threadIdx.x >> 6, lane = threadIdx.x & 63;
  float bias = b_a1[h];
  for (int bb = 0; bb < 8; ++bb) {
    int b = wave * 8 + bb;
    float acc = 0.f;
    for (int k = lane; k < H_; k += 64) acc += wrow[k] * hidden[b * H_ + k];
    #pragma unroll
    for (int off = 32; off; off >>= 1) acc += __shfl_xor(acc, off);
    if (lane == 0) part2[b * H_ + h] = acc + bias;
  }
}

// ---------- scores GEMM: 256x256 tile, BK=64, 8-wave, 8-phase counted-vmcnt ----------
// LDS (dynamic 128KB): A bytes [0,65536) : byte(buf,r,k)=buf*32768+(k>>5)*16384+r*64+(k&31)*2
//                      B bytes [65536,131072): same layout.
// st_16x32 swizzle (byte ^= ((byte>>9)&1)<<5) applied via pre-swizzled global source + swizzled reads.
#define NT_ 16
#define BAR()  __builtin_amdgcn_s_barrier()
#define SB0()  __builtin_amdgcn_sched_barrier(0)
#define VM6()  asm volatile("s_waitcnt vmcnt(6)" ::: "memory")
#define VM0()  asm volatile("s_waitcnt vmcnt(0)" ::: "memory")

#define LOADA(MH) { _Pragma("unroll") for (int m_ = 0; m_ < 4; ++m_) \
  { _Pragma("unroll") for (int ks_ = 0; ks_ < 2; ++ks_) { \
    int r_ = wr*128 + (MH)*64 + m_*16 + l15; \
    int lin_ = ks_*16384 + r_*64 + l16*16; \
    int sw_ = lin_ ^ (((lin_>>9)&1)<<5); \
    af[m_][ks_] = *(const bf16x8*)(smem + buf*32768 + sw_); } } }

#define LOADB() { _Pragma("unroll") for (int n_ = 0; n_ < 4; ++n_) \
  { _Pragma("unroll") for (int ks_ = 0; ks_ < 2; ++ks_) { \
    int r_ = wc*64 + n_*16 + l15; \
    int lin_ = ks_*16384 + r_*64 + l16*16; \
    int sw_ = lin_ ^ (((lin_>>9)&1)<<5); \
    bfr[n_][ks_] = *(const bf16x8*)(smem + 65536 + buf*32768 + sw_); } } }

#define QUAD(MH, NH) { _Pragma("unroll") for (int m_ = 0; m_ < 4; ++m_) \
  { _Pragma("unroll") for (int n_ = 0; n_ < 2; ++n_) { \
    acc[(MH)*4+m_][(NH)*2+n_] = __builtin_amdgcn_mfma_f32_16x16x32_bf16(af[m_][0], bfr[(NH)*2+n_][0], acc[(MH)*4+m_][(NH)*2+n_], 0,0,0); \
    acc[(MH)*4+m_][(NH)*2+n_] = __builtin_amdgcn_mfma_f32_16x16x32_bf16(af[m_][1], bfr[(NH)*2+n_][1], acc[(MH)*4+m_][(NH)*2+n_], 0,0,0); } } }

#define PHASES(T, DO_B1, DO_T2, VMOP) { \
  const int buf = (T) & 1; \
  LOADA(0); LOADB(); \
  if (DO_B1) stB((T)+1, 1, buf^1); \
  BAR(); SB0(); \
  __builtin_amdgcn_s_setprio(1); QUAD(0,0); __builtin_amdgcn_s_setprio(0); \
  SB0(); BAR(); \
  if (DO_T2) stB((T)+2, 0, buf); \
  BAR(); SB0(); \
  __builtin_amdgcn_s_setprio(1); QUAD(0,1); __builtin_amdgcn_s_setprio(0); \
  SB0(); BAR(); \
  LOADA(1); \
  BAR(); SB0(); \
  __builtin_amdgcn_s_setprio(1); QUAD(1,1); __builtin_amdgcn_s_setprio(0); \
  SB0(); BAR(); \
  if (DO_T2) { stA((T)+2, 0, buf); stA((T)+2, 1, buf); } \
  VMOP; \
  BAR(); SB0(); \
  __builtin_amdgcn_s_setprio(1); QUAD(1,0); __builtin_amdgcn_s_setprio(0); \
  SB0(); BAR(); }

__global__ __launch_bounds__(512, 2) void scores_gemm8(
    const unsigned short* __restrict__ A,   // enc_bf [32768][1024]
    const unsigned short* __restrict__ Bm,  // wa1_bf [1024][1024]
    const float* __restrict__ part2,        // [32][1024]
    const float* __restrict__ wa2,          // [1024]
    float* __restrict__ partials)           // [32768][16]
{
  extern __shared__ char smem[];
  const int tid = threadIdx.x;
  const int wave = tid >> 6, lane = tid & 63;
  const int wr = wave >> 2, wc = wave & 3;
  const int l15 = lane & 15, l16 = lane >> 4;
  const int bm = blockIdx.x, bn = blockIdx.y;

  const unsigned short* Abase = A  + (size_t)(bm * 256) * 1024;
  const unsigned short* Bbase = Bm + (size_t)(bn * 256) * 1024;

  // staging: thread tid stages 16B granule Lc=tid*16 of panel0 and panel1 of a half.
  // LDS dest linear; source pre-swizzled (rule #21).
  const int Lc = tid * 16;
  const int Ls = Lc ^ (((Lc >> 9) & 1) << 5);
  const int sr = Ls >> 6;            // row within half (0..127)
  const int sk = (Ls >> 1) & 31;     // k within panel

  auto stA = [&](int t, int h, int db) {
    char* base = smem + db * 32768 + h * 8192 + Lc;
    const unsigned short* src = Abase + (size_t)(h * 128 + sr) * 1024 + t * 64 + sk;
    async16(base,         src);
    async16(base + 16384, src + 32);
  };
  auto stB = [&](int t, int h, int db) {
    char* base = smem + 65536 + db * 32768 + h * 8192 + Lc;
    const unsigned short* src = Bbase + (size_t)(h * 128 + sr) * 1024 + t * 64 + sk;
    async16(base,         src);
    async16(base + 16384, src + 32);
  };

  f32x4 acc[8][4];
  #pragma unroll
  for (int i = 0; i < 8; ++i)
    #pragma unroll
    for (int j = 0; j < 4; ++j) acc[i][j] = (f32x4){0.f, 0.f, 0.f, 0.f};
  bf16x8 af[4][2], bfr[4][2];

  // prologue: tile0 all 4 halves, tile1 {B0, A0, A1}; leave 3 halves in flight
  stA(0, 0, 0); stA(0, 1, 0); stB(0, 0, 0); stB(0, 1, 0);
  stB(1, 0, 1); stA(1, 0, 1); stA(1, 1, 1);
  VM6();
  BAR();

  #pragma unroll 1
  for (int t = 0; t < NT_ - 2; ++t) PHASES(t, 1, 1, VM6());
  PHASES(NT_ - 2, 1, 0, VM0());
  PHASES(NT_ - 1, 0, 0, (void)0);

  // fused epilogue: partials[row][bn*4+wc] = sum over this 64-col group of wa2*tanh(acc+part2)
  const int b = bm >> 2;
  float w2[4], p2[4];
  #pragma unroll
  for (int ni = 0; ni < 4; ++ni) {
    int col = bn * 256 + wc * 64 + ni * 16 + l15;
    w2[ni] = wa2[col];
    p2[ni] = part2[b * H_ + col];
  }
  #pragma unroll
  for (int mi = 0; mi < 8; ++mi) {
    #pragma unroll
    for (int r = 0; r < 4; ++r) {
      float s = 0.f;
      #pragma unroll
      for (int ni = 0; ni < 4; ++ni)
        s += w2[ni] * tanhf(acc[mi][ni][r] + p2[ni]);
      s += __shfl_xor(s, 1); s += __shfl_xor(s, 2);
      s += __shfl_xor(s, 4); s += __shfl_xor(s, 8);
      if (l15 == 0) {
        int row = bm * 256 + wr * 128 + mi * 16 + l16 * 4 + r;
        partials[(size_t)row * 16 + bn * 4 + wc] = s;
      }
    }
  }
}

// ---------- softmax over S per b ----------
__global__ void softmax_kernel(const float* __restrict__ partials, const float* __restrict__ b_a2,
                               float* __restrict__ attn) {
  int b = blockIdx.x, s = threadIdx.x;       // block 1024
  int lane = s & 63, wid = s >> 6;
  const float4* p = (const float4*)(partials + (size_t)(b * S_ + s) * 16);
  float sc = b_a2[0];
  #pragma unroll
  for (int i = 0; i < 4; ++i) { float4 v = p[i]; sc += v.x + v.y + v.z + v.w; }
  __shared__ float rmax[16], rsum[16];
  float m = sc;
  #pragma unroll
  for (int off = 32; off; off >>= 1) m = fmaxf(m, __shfl_xor(m, off));
  if (lane == 0) rmax[wid] = m;
  __syncthreads();
  float M = rmax[0];
  #pragma unroll
  for (int i = 1; i < 16; ++i) M = fmaxf(M, rmax[i]);
  float e = expf(sc - M);
  float su = e;
  #pragma unroll
  for (int off = 32; off; off >>= 1) su += __shfl_xor(su, off);
  if (lane == 0) rsum[wid] = su;
  __syncthreads();
  float T = 0.f;
  #pragma unroll
  for (int i = 0; i < 16; ++i) T += rsum[i];
  attn[b * S_ + s] = e / T;
}

// ---------- context partials over 64-row s-chunks ----------
__global__ void ctx_partial_kernel(const unsigned short* __restrict__ encbf,
                                   const float* __restrict__ attn, float* __restrict__ ctxp) {
  int sc = blockIdx.x, b = blockIdx.y, t = threadIdx.x;
  int h4 = t * 4;
  float a0 = 0, a1 = 0, a2 = 0, a3 = 0;
  const unsigned short* base = encbf + (size_t)b * S_ * H_ + h4;
  const float* aw = attn + b * S_ + sc * 64;
  #pragma unroll 4
  for (int i = 0; i < 64; ++i) {
    float w = aw[i];
    ushort4 ev = *(const ushort4*)(base + (size_t)(sc * 64 + i) * H_);
    a0 += w * b2f(ev.x); a1 += w * b2f(ev.y); a2 += w * b2f(ev.z); a3 += w * b2f(ev.w);
  }
  float4 o = {a0, a1, a2, a3};
  *(float4*)(ctxp + (size_t)(sc * B_ + b) * H_ + h4) = o;
}

// ---------- prep: reduce ctx (16 chunks), build ec_bf, hprev_bf ----------
__global__ void prep_kernel(const float* __restrict__ ctxp, const float* __restrict__ emb,
                            const int* __restrict__ word, const float* __restrict__ hidden,
                            unsigned short* __restrict__ ec_bf, unsigned short* __restrict__ hprev_bf) {
  int b = blockIdx.x;
  int w = word[b];
  for (int h = threadIdx.x; h < H_; h += 256) {
    float c = 0.f;
    #pragma unroll
    for (int sc = 0; sc < 16; ++sc) c += ctxp[(size_t)(sc * B_ + b) * H_ + h];
    ec_bf[b * 2048 + 1024 + h] = f2b(c);
    ec_bf[b * 2048 + h] = f2b(emb[(size_t)w * H_ + h]);
    hprev_bf[b * H_ + h] = f2b(hidden[b * H_ + h]);
  }
}

// ---------- skinny MFMA GEMM: C[32,N] = A_bf[32,K] @ Bf32[N,K]^T ----------
__global__ __launch_bounds__(256) void skinny_gemm(
    const unsigned short* __restrict__ A, const float* __restrict__ Bw,
    float* __restrict__ C, const float* __restrict__ bias,
    int N, int K, int KC, int ldc, int mode)
{
  int n0 = blockIdx.x * 64;
  int kc = blockIdx.y;
  int wave = threadIdx.x >> 6, lane = threadIdx.x & 63;
  int l15 = lane & 15, l16 = lane >> 4;
  int col = n0 + wave * 16 + l15;
  int vclamp = col < N ? col : N - 1;
  const unsigned short* a0p = A + l15 * K + l16 * 8;
  const unsigned short* a1p = A + (16 + l15) * K + l16 * 8;
  const float* bp = Bw + (size_t)vclamp * K + l16 * 8;
  f32x4 acc0 = {0.f, 0.f, 0.f, 0.f}, acc1 = {0.f, 0.f, 0.f, 0.f};
  int k0 = kc * KC, k1 = (k0 + KC < K) ? (k0 + KC) : K;
  #pragma unroll 4
  for (int k = k0; k < k1; k += 32) {
    bf16x8 a0 = *(const bf16x8*)(a0p + k);
    bf16x8 a1 = *(const bf16x8*)(a1p + k);
    float4 bv0 = *(const float4*)(bp + k);
    float4 bv1 = *(const float4*)(bp + k + 4);
    bf16x8 bb;
    bb[0] = (short)f2b(bv0.x); bb[1] = (short)f2b(bv0.y);
    bb[2] = (short)f2b(bv0.z); bb[3] = (short)f2b(bv0.w);
    bb[4] = (short)f2b(bv1.x); bb[5] = (short)f2b(bv1.y);
    bb[6] = (short)f2b(bv1.z); bb[7] = (short)f2b(bv1.w);
    acc0 = __builtin_amdgcn_mfma_f32_16x16x32_bf16(a0, bb, acc0, 0, 0, 0);
    acc1 = __builtin_amdgcn_mfma_f32_16x16x32_bf16(a1, bb, acc1, 0, 0, 0);
  }
  if (col < N) {
    #pragma unroll
    for (int r = 0; r < 4; ++r) {
      int m = l16 * 4 + r;
      if (mode == 1) {
        float bv = bias[col];
        C[(size_t)m * ldc + col] = acc0[r] + bv;
        C[(size_t)(16 + m) * ldc + col] = acc1[r] + bv;
      } else {
        C[(size_t)(kc * 32 + m) * N + col] = acc0[r];
        C[(size_t)(kc * 32 + 16 + m) * N + col] = acc1[r];
      }
    }
  }
}

// ---------- x = relu(sum_kc xp + b_c) -> bf16 (16 chunks) ----------
__global__ void xfinish_kernel(const float* __restrict__ xp, const float* __restrict__ b_c,
                               unsigned short* __restrict__ x_bf) {
  int i = blockIdx.x * 256 + threadIdx.x;   // 32768
  int b = i >> 10, h = i & 1023;
  float v = b_c[h];
  #pragma unroll
  for (int kc = 0; kc < 16; ++kc) v += xp[(size_t)(kc * B_ + b) * H_ + h];
  x_bf[i] = f2b(v > 0.f ? v : 0.f);
}

// ---------- GRU gates + h_new (8 chunks) ----------
__global__ void gates_kernel(const float* __restrict__ gip, const float* __restrict__ ghp,
                             const float* __restrict__ b_ih, const float* __restrict__ b_hh,
                             const float* __restrict__ hidden, float* __restrict__ hnew_out,
                             unsigned short* __restrict__ hr_bf) {
  int i = blockIdx.x * 256 + threadIdx.x;   // 32768
  int b = i >> 10, h = i & 1023;
  float g[6];
  #pragma unroll
  for (int t = 0; t < 3; ++t) {
    int j = h + t * H_;
    float vi = b_ih[j], vh = b_hh[j];
    #pragma unroll
    for (int kc = 0; kc < 8; ++kc) {
      vi += gip[(size_t)(kc * B_ + b) * 3072 + j];
      vh += ghp[(size_t)(kc * B_ + b) * 3072 + j];
    }
    g[t] = vi; g[3 + t] = vh;
  }
  float r = 1.f / (1.f + expf(-(g[0] + g[3])));
  float z = 1.f / (1.f + expf(-(g[1] + g[4])));
  float n = tanhf(g[2] + r * g[5]);
  float hv = (1.f - z) * n + z * hidden[i];
  hnew_out[i] = hv;
  hr_bf[i] = f2b(hv > 0.f ? hv : 0.f);
}

extern "C" void kernel_launch(void* const* d_in, const int* in_sizes, int n_in,
                              void* d_out, int out_size, void* d_ws, size_t ws_size,
                              hipStream_t stream) {
  const int*   word   = (const int*)  d_in[0];
  const float* hidden = (const float*)d_in[1];
  const float* enc    = (const float*)d_in[2];
  const float* emb    = (const float*)d_in[3];
  const float* W_a1   = (const float*)d_in[4];
  const float* b_a1   = (const float*)d_in[5];
  const float* W_a2   = (const float*)d_in[6];
  const float* b_a2   = (const float*)d_in[7];
  const float* W_c    = (const float*)d_in[8];
  const float* b_c    = (const float*)d_in[9];
  const float* W_ih   = (const float*)d_in[10];
  const float* W_hh   = (const float*)d_in[11];
  const float* b_ih   = (const float*)d_in[12];
  const float* b_hh   = (const float*)d_in[13];
  const float* W_fc   = (const float*)d_in[14];
  const float* b_fc   = (const float*)d_in[15];
  float* out = (float*)d_out;

  if (ws_size < 71892992ull) return;  // loud failure

  char* ws = (char*)d_ws;
  // overlays (stream-ordered lifetimes):
  unsigned short* enc_bf   = (unsigned short*)(ws + 0);         // dead after ctx_partial
  float*          gip      = (float*)         (ws + 0);         // 3MB, after enc_bf dead
  float*          ghp      = (float*)         (ws + 3145728);   // 3MB
  unsigned short* wa1_bf   = (unsigned short*)(ws + 67108864);  // dead after scores
  float*          xp       = (float*)         (ws + 67108864);  // 2MB, after wa1_bf dead
  float*          part2    = (float*)         (ws + 69206016);
  float*          partials = (float*)         (ws + 69337088);  // dead after softmax
  float*          ctxp     = (float*)         (ws + 69337088);  // 2MB, after partials dead
  float*          attn     = (float*)         (ws + 71434240);
  unsigned short* ec_bf    = (unsigned short*)(ws + 71565312);
  unsigned short* hprev_bf = (unsigned short*)(ws + 71696384);
  unsigned short* x_bf     = (unsigned short*)(ws + 71761920);
  unsigned short* hr_bf    = (unsigned short*)(ws + 71827456);

  hipFuncSetAttribute((const void*)scores_gemm8,
                      hipFuncAttributeMaxDynamicSharedMemorySize, 131072);

  conv_f32_bf16<<<dim3(16384), dim3(256), 0, stream>>>(enc, enc_bf);
  conv_wa1<<<dim3(512), dim3(256), 0, stream>>>(W_a1, wa1_bf);
  part2_kernel<<<dim3(1024), dim3(256), 0, stream>>>(W_a1, hidden, b_a1, part2);
  scores_gemm8<<<dim3(128, 4), dim3(512), 131072, stream>>>(enc_bf, wa1_bf, part2, W_a2, partials);
  softmax_kernel<<<dim3(32), dim3(1024), 0, stream>>>(partials, b_a2, attn);
  ctx_partial_kernel<<<dim3(16, 32), dim3(256), 0, stream>>>(enc_bf, attn, ctxp);
  prep_kernel<<<dim3(32), dim3(256), 0, stream>>>(ctxp, emb, word, hidden, ec_bf, hprev_bf);
  skinny_gemm<<<dim3(16, 16), dim3(256), 0, stream>>>(ec_bf, W_c, xp, (const float*)nullptr,
                                                      1024, 2048, 128, 0, 0);
  xfinish_kernel<<<dim3(128), dim3(256), 0, stream>>>(xp, b_c, x_bf);
  skinny_gemm<<<dim3(48, 8), dim3(256), 0, stream>>>(x_bf, W_ih, gip, (const float*)nullptr,
                                                     3072, 1024, 128, 0, 0);
  skinny_gemm<<<dim3(48, 8), dim3(256), 0, stream>>>(hprev_bf, W_hh, ghp, (const float*)nullptr,
                                                     3072, 1024, 128, 0, 0);
  gates_kernel<<<dim3(128), dim3(256), 0, stream>>>(gip, ghp, b_ih, b_hh, hidden,
                                                    out + (size_t)B_ * V_, hr_bf);
  skinny_gemm<<<dim3(786, 1), dim3(256), 0, stream>>>(hr_bf, W_fc, out, b_fc,
                                                      V_, 1024, 1024, V_, 1);
}

// Round 3
// 288.156 us; speedup vs baseline: 1.0611x; 1.0109x over previous
//
#include <hip/hip_runtime.h>

#define B_  32
#define S_  1024
#define H_  1024
#define V_  50257

typedef __attribute__((ext_vector_type(8))) short bf16x8;
typedef __attribute__((ext_vector_type(4))) float f32x4;
typedef __attribute__((ext_vector_type(8))) unsigned short u16x8;

__device__ __forceinline__ unsigned short f2b(float f) {
  union { float f; unsigned u; } v; v.f = f;
  unsigned r = 0x7FFFu + ((v.u >> 16) & 1u);
  return (unsigned short)((v.u + r) >> 16);
}
__device__ __forceinline__ float b2f(unsigned short h) {
  union { unsigned u; float f; } v; v.u = ((unsigned)h) << 16;
  return v.f;
}

__device__ __forceinline__ void async16(void* lds, const void* g) {
  typedef __attribute__((address_space(3))) void as3_void;
  typedef __attribute__((address_space(1))) void as1_void;
  as3_void* l = (as3_void*)(unsigned)(unsigned long long)lds;
  const as1_void* s = (const as1_void*)(unsigned long long)g;
  __builtin_amdgcn_global_load_lds(s, l, 16, 0, 0);
}

// ---------- enc f32 -> bf16 ----------
__global__ void conv_f32_bf16(const float* __restrict__ src, unsigned short* __restrict__ dst) {
  size_t i = ((size_t)blockIdx.x * 256 + threadIdx.x) * 8;
  float4 v0 = *(const float4*)(src + i);
  float4 v1 = *(const float4*)(src + i + 4);
  u16x8 o;
  o[0]=f2b(v0.x); o[1]=f2b(v0.y); o[2]=f2b(v0.z); o[3]=f2b(v0.w);
  o[4]=f2b(v1.x); o[5]=f2b(v1.y); o[6]=f2b(v1.z); o[7]=f2b(v1.w);
  *(u16x8*)(dst + i) = o;
}

// ---------- fused: wa1 enc-half -> bf16  AND  part2[b][h] ----------
__global__ void wa1_prep_kernel(const float* __restrict__ wa1, const float* __restrict__ hidden,
                                const float* __restrict__ b_a1,
                                unsigned short* __restrict__ wa1_bf, float* __restrict__ part2) {
  int h = blockIdx.x;                       // 1024 blocks, 256 threads
  int tid = threadIdx.x;
  // convert cols 0..1023 of row h
  {
    int c = tid * 4;
    float4 v = *(const float4*)(wa1 + (size_t)h * 2048 + c);
    ushort4 o;
    o.x = f2b(v.x); o.y = f2b(v.y); o.z = f2b(v.z); o.w = f2b(v.w);
    *(ushort4*)(wa1_bf + (size_t)h * 1024 + c) = o;
  }
  // part2: dot of cols 1024..2047 with hidden rows
  __shared__ float wrow[H_];
  {
    int c = tid * 4;
    float4 v = *(const float4*)(wa1 + (size_t)h * 2048 + 1024 + c);
    wrow[c] = v.x; wrow[c+1] = v.y; wrow[c+2] = v.z; wrow[c+3] = v.w;
  }
  __syncthreads();
  int wave = tid >> 6, lane = tid & 63;
  float bias = b_a1[h];
  for (int bb = 0; bb < 8; ++bb) {
    int b = wave * 8 + bb;
    float acc = 0.f;
    for (int k = lane; k < H_; k += 64) acc += wrow[k] * hidden[b * H_ + k];
    #pragma unroll
    for (int off = 32; off; off >>= 1) acc += __shfl_xor(acc, off);
    if (lane == 0) part2[b * H_ + h] = acc + bias;
  }
}

// ---------- scores GEMM: 256x256 tile, BK=64, 8-wave, 8-phase counted-vmcnt ----------
// LDS (dynamic 128KB): A [0,65536): byte(buf,h,r,k) = buf*32768 + h*16384 + r*128 + k*2
//                      B [65536,131072): same. r in [0,128) per half, k in [0,64).
// st_16x32 swizzle: byte ^= ((byte>>9)&1)<<5  (within the 16KB half-tile) -- m201 geometry.
// Stage side: linear LDS dest + inverse-swizzled global source (rule #21).
#define NT_ 16
#define BAR()  __builtin_amdgcn_s_barrier()
#define SB0()  __builtin_amdgcn_sched_barrier(0)
#define VM6()  asm volatile("s_waitcnt vmcnt(6)" ::: "memory")
#define VM0()  asm volatile("s_waitcnt vmcnt(0)" ::: "memory")

#define LOADA(MH) { _Pragma("unroll") for (int m_ = 0; m_ < 4; ++m_) \
  { _Pragma("unroll") for (int ks_ = 0; ks_ < 2; ++ks_) { \
    int lr_ = (MH)*64 + m_*16 + l15; \
    int lin_ = lr_*128 + ks_*64 + l16*16; \
    int sw_ = lin_ ^ (((lin_>>9)&1)<<5); \
    af[m_][ks_] = *(const bf16x8*)(smem + buf*32768 + wr*16384 + sw_); } } }

#define LOADB() { _Pragma("unroll") for (int n_ = 0; n_ < 4; ++n_) \
  { _Pragma("unroll") for (int ks_ = 0; ks_ < 2; ++ks_) { \
    int lr_ = (wc&1)*64 + n_*16 + l15; \
    int lin_ = lr_*128 + ks_*64 + l16*16; \
    int sw_ = lin_ ^ (((lin_>>9)&1)<<5); \
    bfr[n_][ks_] = *(const bf16x8*)(smem + 65536 + buf*32768 + (wc>>1)*16384 + sw_); } } }

#define QUAD(MH, NH) { _Pragma("unroll") for (int m_ = 0; m_ < 4; ++m_) \
  { _Pragma("unroll") for (int n_ = 0; n_ < 2; ++n_) { \
    acc[(MH)*4+m_][(NH)*2+n_] = __builtin_amdgcn_mfma_f32_16x16x32_bf16(af[m_][0], bfr[(NH)*2+n_][0], acc[(MH)*4+m_][(NH)*2+n_], 0,0,0); \
    acc[(MH)*4+m_][(NH)*2+n_] = __builtin_amdgcn_mfma_f32_16x16x32_bf16(af[m_][1], bfr[(NH)*2+n_][1], acc[(MH)*4+m_][(NH)*2+n_], 0,0,0); } } }

#define PHASES(T, DO_B1, DO_T2, VMOP) { \
  const int buf = (T) & 1; \
  LOADA(0); LOADB(); \
  if (DO_B1) stB((T)+1, 1, buf^1); \
  BAR(); SB0(); \
  __builtin_amdgcn_s_setprio(1); QUAD(0,0); __builtin_amdgcn_s_setprio(0); \
  SB0(); BAR(); \
  if (DO_T2) stB((T)+2, 0, buf); \
  BAR(); SB0(); \
  __builtin_amdgcn_s_setprio(1); QUAD(0,1); __builtin_amdgcn_s_setprio(0); \
  SB0(); BAR(); \
  LOADA(1); \
  BAR(); SB0(); \
  __builtin_amdgcn_s_setprio(1); QUAD(1,1); __builtin_amdgcn_s_setprio(0); \
  SB0(); BAR(); \
  if (DO_T2) { stA((T)+2, 0, buf); stA((T)+2, 1, buf); } \
  VMOP; \
  BAR(); SB0(); \
  __builtin_amdgcn_s_setprio(1); QUAD(1,0); __builtin_amdgcn_s_setprio(0); \
  SB0(); BAR(); }

__global__ __launch_bounds__(512, 2) void scores_gemm8(
    const unsigned short* __restrict__ A,   // enc_bf [32768][1024]
    const unsigned short* __restrict__ Bm,  // wa1_bf [1024][1024]
    const float* __restrict__ part2,        // [32][1024]
    const float* __restrict__ wa2,          // [1024]
    float* __restrict__ partials)           // [32768][16]
{
  extern __shared__ char smem[];
  const int tid = threadIdx.x;
  const int wave = tid >> 6, lane = tid & 63;
  const int wr = wave >> 2, wc = wave & 3;
  const int l15 = lane & 15, l16 = lane >> 4;
  const int bm = blockIdx.x, bn = blockIdx.y;

  const unsigned short* Abase = A  + (size_t)(bm * 256) * 1024;
  const unsigned short* Bbase = Bm + (size_t)(bn * 256) * 1024;

  // staging: thread covers 16B granules at L and L+8192 of the 16KB half-tile.
  const int Lc = tid * 16;
  const int Ls = Lc ^ (((Lc >> 9) & 1) << 5);
  const int sr = Ls >> 7;            // row within half (0..63 for granule 1)
  const int sk = (Ls & 127) >> 1;    // col (bf16 units, multiple of 8)

  auto stA = [&](int t, int h, int db) {
    char* dst = smem + db * 32768 + h * 16384 + Lc;
    const unsigned short* src = Abase + (size_t)(h * 128 + sr) * 1024 + t * 64 + sk;
    async16(dst,        src);
    async16(dst + 8192, src + 64 * 1024);   // rows 64..127, same swizzle (bit9 unaffected by +8192)
  };
  auto stB = [&](int t, int h, int db) {
    char* dst = smem + 65536 + db * 32768 + h * 16384 + Lc;
    const unsigned short* src = Bbase + (size_t)(h * 128 + sr) * 1024 + t * 64 + sk;
    async16(dst,        src);
    async16(dst + 8192, src + 64 * 1024);
  };

  f32x4 acc[8][4];
  #pragma unroll
  for (int i = 0; i < 8; ++i)
    #pragma unroll
    for (int j = 0; j < 4; ++j) acc[i][j] = (f32x4){0.f, 0.f, 0.f, 0.f};
  bf16x8 af[4][2], bfr[4][2];

  // prologue: tile0 all 4 halves, tile1 {B0, A0, A1}; leaves 3 half-tiles in flight
  stA(0, 0, 0); stA(0, 1, 0); stB(0, 0, 0); stB(0, 1, 0);
  stB(1, 0, 1); stA(1, 0, 1); stA(1, 1, 1);
  VM6();
  BAR();

  #pragma unroll 1
  for (int t = 0; t < NT_ - 2; ++t) PHASES(t, 1, 1, VM6());
  PHASES(NT_ - 2, 1, 0, VM0());
  PHASES(NT_ - 1, 0, 0, (void)0);

  // fused epilogue: partials[row][bn*4+wc] = sum over 64-col group of wa2*tanh(acc+part2)
  const int b = bm >> 2;
  float w2[4], p2[4];
  #pragma unroll
  for (int ni = 0; ni < 4; ++ni) {
    int col = bn * 256 + wc * 64 + ni * 16 + l15;
    w2[ni] = wa2[col];
    p2[ni] = part2[b * H_ + col];
  }
  #pragma unroll
  for (int mi = 0; mi < 8; ++mi) {
    #pragma unroll
    for (int r = 0; r < 4; ++r) {
      float s = 0.f;
      #pragma unroll
      for (int ni = 0; ni < 4; ++ni)
        s += w2[ni] * tanhf(acc[mi][ni][r] + p2[ni]);
      s += __shfl_xor(s, 1); s += __shfl_xor(s, 2);
      s += __shfl_xor(s, 4); s += __shfl_xor(s, 8);
      if (l15 == 0) {
        int row = bm * 256 + wr * 128 + mi * 16 + l16 * 4 + r;
        partials[(size_t)row * 16 + bn * 4 + wc] = s;
      }
    }
  }
}

// ---------- softmax over S per b ----------
__global__ void softmax_kernel(const float* __restrict__ partials, const float* __restrict__ b_a2,
                               float* __restrict__ attn) {
  int b = blockIdx.x, s = threadIdx.x;       // block 1024
  int lane = s & 63, wid = s >> 6;
  const float4* p = (const float4*)(partials + (size_t)(b * S_ + s) * 16);
  float sc = b_a2[0];
  #pragma unroll
  for (int i = 0; i < 4; ++i) { float4 v = p[i]; sc += v.x + v.y + v.z + v.w; }
  __shared__ float rmax[16], rsum[16];
  float m = sc;
  #pragma unroll
  for (int off = 32; off; off >>= 1) m = fmaxf(m, __shfl_xor(m, off));
  if (lane == 0) rmax[wid] = m;
  __syncthreads();
  float M = rmax[0];
  #pragma unroll
  for (int i = 1; i < 16; ++i) M = fmaxf(M, rmax[i]);
  float e = expf(sc - M);
  float su = e;
  #pragma unroll
  for (int off = 32; off; off >>= 1) su += __shfl_xor(su, off);
  if (lane == 0) rsum[wid] = su;
  __syncthreads();
  float T = 0.f;
  #pragma unroll
  for (int i = 0; i < 16; ++i) T += rsum[i];
  attn[b * S_ + s] = e / T;
}

// ---------- context partials over 64-row s-chunks ----------
__global__ void ctx_partial_kernel(const unsigned short* __restrict__ encbf,
                                   const float* __restrict__ attn, float* __restrict__ ctxp) {
  int sc = blockIdx.x, b = blockIdx.y, t = threadIdx.x;
  int h4 = t * 4;
  float a0 = 0, a1 = 0, a2 = 0, a3 = 0;
  const unsigned short* base = encbf + (size_t)b * S_ * H_ + h4;
  const float* aw = attn + b * S_ + sc * 64;
  #pragma unroll 4
  for (int i = 0; i < 64; ++i) {
    float w = aw[i];
    ushort4 ev = *(const ushort4*)(base + (size_t)(sc * 64 + i) * H_);
    a0 += w * b2f(ev.x); a1 += w * b2f(ev.y); a2 += w * b2f(ev.z); a3 += w * b2f(ev.w);
  }
  float4 o = {a0, a1, a2, a3};
  *(float4*)(ctxp + (size_t)(sc * B_ + b) * H_ + h4) = o;
}

// ---------- prep: reduce ctx (16 chunks), build ec_bf, hprev_bf ----------
__global__ void prep_kernel(const float* __restrict__ ctxp, const float* __restrict__ emb,
                            const int* __restrict__ word, const float* __restrict__ hidden,
                            unsigned short* __restrict__ ec_bf, unsigned short* __restrict__ hprev_bf) {
  int b = blockIdx.x;
  int w = word[b];
  for (int h = threadIdx.x; h < H_; h += 256) {
    float c = 0.f;
    #pragma unroll
    for (int sc = 0; sc < 16; ++sc) c += ctxp[(size_t)(sc * B_ + b) * H_ + h];
    ec_bf[b * 2048 + 1024 + h] = f2b(c);
    ec_bf[b * 2048 + h] = f2b(emb[(size_t)w * H_ + h]);
    hprev_bf[b * H_ + h] = f2b(hidden[b * H_ + h]);
  }
}

// ---------- skinny MFMA GEMM: C[32,N] = A_bf[32,K] @ Bf32[N,K]^T ----------
__global__ __launch_bounds__(256) void skinny_gemm(
    const unsigned short* __restrict__ A, const float* __restrict__ Bw,
    float* __restrict__ C, const float* __restrict__ bias,
    int N, int K, int KC, int ldc, int mode)
{
  int n0 = blockIdx.x * 64;
  int kc = blockIdx.y;
  int wave = threadIdx.x >> 6, lane = threadIdx.x & 63;
  int l15 = lane & 15, l16 = lane >> 4;
  int col = n0 + wave * 16 + l15;
  int vclamp = col < N ? col : N - 1;
  const unsigned short* a0p = A + l15 * K + l16 * 8;
  const unsigned short* a1p = A + (16 + l15) * K + l16 * 8;
  const float* bp = Bw + (size_t)vclamp * K + l16 * 8;
  f32x4 acc0 = {0.f, 0.f, 0.f, 0.f}, acc1 = {0.f, 0.f, 0.f, 0.f};
  int k0 = kc * KC, k1 = (k0 + KC < K) ? (k0 + KC) : K;
  #pragma unroll 4
  for (int k = k0; k < k1; k += 32) {
    bf16x8 a0 = *(const bf16x8*)(a0p + k);
    bf16x8 a1 = *(const bf16x8*)(a1p + k);
    float4 bv0 = *(const float4*)(bp + k);
    float4 bv1 = *(const float4*)(bp + k + 4);
    bf16x8 bb;
    bb[0] = (short)f2b(bv0.x); bb[1] = (short)f2b(bv0.y);
    bb[2] = (short)f2b(bv0.z); bb[3] = (short)f2b(bv0.w);
    bb[4] = (short)f2b(bv1.x); bb[5] = (short)f2b(bv1.y);
    bb[6] = (short)f2b(bv1.z); bb[7] = (short)f2b(bv1.w);
    acc0 = __builtin_amdgcn_mfma_f32_16x16x32_bf16(a0, bb, acc0, 0, 0, 0);
    acc1 = __builtin_amdgcn_mfma_f32_16x16x32_bf16(a1, bb, acc1, 0, 0, 0);
  }
  if (col < N) {
    #pragma unroll
    for (int r = 0; r < 4; ++r) {
      int m = l16 * 4 + r;
      if (mode == 1) {
        float bv = bias[col];
        C[(size_t)m * ldc + col] = acc0[r] + bv;
        C[(size_t)(16 + m) * ldc + col] = acc1[r] + bv;
      } else {
        C[(size_t)(kc * 32 + m) * N + col] = acc0[r];
        C[(size_t)(kc * 32 + 16 + m) * N + col] = acc1[r];
      }
    }
  }
}

// ---------- fused W_ih / W_hh skinny GEMM (blockIdx.z selects) ----------
__global__ __launch_bounds__(256) void ihhh_gemm(
    const unsigned short* __restrict__ x_bf, const unsigned short* __restrict__ hprev_bf,
    const float* __restrict__ W_ih, const float* __restrict__ W_hh,
    float* __restrict__ gip, float* __restrict__ ghp)
{
  const unsigned short* A = blockIdx.z ? hprev_bf : x_bf;
  const float* Bw = blockIdx.z ? W_hh : W_ih;
  float* C = blockIdx.z ? ghp : gip;
  const int N = 3072, K = 1024, KC = 128;
  int n0 = blockIdx.x * 64;
  int kc = blockIdx.y;
  int wave = threadIdx.x >> 6, lane = threadIdx.x & 63;
  int l15 = lane & 15, l16 = lane >> 4;
  int col = n0 + wave * 16 + l15;
  const unsigned short* a0p = A + l15 * K + l16 * 8;
  const unsigned short* a1p = A + (16 + l15) * K + l16 * 8;
  const float* bp = Bw + (size_t)col * K + l16 * 8;
  f32x4 acc0 = {0.f, 0.f, 0.f, 0.f}, acc1 = {0.f, 0.f, 0.f, 0.f};
  int k0 = kc * KC;
  #pragma unroll 4
  for (int k = k0; k < k0 + KC; k += 32) {
    bf16x8 a0 = *(const bf16x8*)(a0p + k);
    bf16x8 a1 = *(const bf16x8*)(a1p + k);
    float4 bv0 = *(const float4*)(bp + k);
    float4 bv1 = *(const float4*)(bp + k + 4);
    bf16x8 bb;
    bb[0] = (short)f2b(bv0.x); bb[1] = (short)f2b(bv0.y);
    bb[2] = (short)f2b(bv0.z); bb[3] = (short)f2b(bv0.w);
    bb[4] = (short)f2b(bv1.x); bb[5] = (short)f2b(bv1.y);
    bb[6] = (short)f2b(bv1.z); bb[7] = (short)f2b(bv1.w);
    acc0 = __builtin_amdgcn_mfma_f32_16x16x32_bf16(a0, bb, acc0, 0, 0, 0);
    acc1 = __builtin_amdgcn_mfma_f32_16x16x32_bf16(a1, bb, acc1, 0, 0, 0);
  }
  #pragma unroll
  for (int r = 0; r < 4; ++r) {
    int m = l16 * 4 + r;
    C[(size_t)(kc * 32 + m) * N + col] = acc0[r];
    C[(size_t)(kc * 32 + 16 + m) * N + col] = acc1[r];
  }
}

// ---------- x = relu(sum_kc xp + b_c) -> bf16 (16 chunks) ----------
__global__ void xfinish_kernel(const float* __restrict__ xp, const float* __restrict__ b_c,
                               unsigned short* __restrict__ x_bf) {
  int i = blockIdx.x * 256 + threadIdx.x;   // 32768
  int b = i >> 10, h = i & 1023;
  float v = b_c[h];
  #pragma unroll
  for (int kc = 0; kc < 16; ++kc) v += xp[(size_t)(kc * B_ + b) * H_ + h];
  x_bf[i] = f2b(v > 0.f ? v : 0.f);
}

// ---------- GRU gates + h_new (8 chunks) ----------
__global__ void gates_kernel(const float* __restrict__ gip, const float* __restrict__ ghp,
                             const float* __restrict__ b_ih, const float* __restrict__ b_hh,
                             const float* __restrict__ hidden, float* __restrict__ hnew_out,
                             unsigned short* __restrict__ hr_bf) {
  int i = blockIdx.x * 256 + threadIdx.x;   // 32768
  int b = i >> 10, h = i & 1023;
  float g[6];
  #pragma unroll
  for (int t = 0; t < 3; ++t) {
    int j = h + t * H_;
    float vi = b_ih[j], vh = b_hh[j];
    #pragma unroll
    for (int kc = 0; kc < 8; ++kc) {
      vi += gip[(size_t)(kc * B_ + b) * 3072 + j];
      vh += ghp[(size_t)(kc * B_ + b) * 3072 + j];
    }
    g[t] = vi; g[3 + t] = vh;
  }
  float r = 1.f / (1.f + expf(-(g[0] + g[3])));
  float z = 1.f / (1.f + expf(-(g[1] + g[4])));
  float n = tanhf(g[2] + r * g[5]);
  float hv = (1.f - z) * n + z * hidden[i];
  hnew_out[i] = hv;
  hr_bf[i] = f2b(hv > 0.f ? hv : 0.f);
}

extern "C" void kernel_launch(void* const* d_in, const int* in_sizes, int n_in,
                              void* d_out, int out_size, void* d_ws, size_t ws_size,
                              hipStream_t stream) {
  const int*   word   = (const int*)  d_in[0];
  const float* hidden = (const float*)d_in[1];
  const float* enc    = (const float*)d_in[2];
  const float* emb    = (const float*)d_in[3];
  const float* W_a1   = (const float*)d_in[4];
  const float* b_a1   = (const float*)d_in[5];
  const float* W_a2   = (const float*)d_in[6];
  const float* b_a2   = (const float*)d_in[7];
  const float* W_c    = (const float*)d_in[8];
  const float* b_c    = (const float*)d_in[9];
  const float* W_ih   = (const float*)d_in[10];
  const float* W_hh   = (const float*)d_in[11];
  const float* b_ih   = (const float*)d_in[12];
  const float* b_hh   = (const float*)d_in[13];
  const float* W_fc   = (const float*)d_in[14];
  const float* b_fc   = (const float*)d_in[15];
  float* out = (float*)d_out;

  if (ws_size < 71892992ull) return;  // loud failure

  char* ws = (char*)d_ws;
  // overlays (stream-ordered lifetimes):
  unsigned short* enc_bf   = (unsigned short*)(ws + 0);         // dead after ctx_partial
  float*          gip      = (float*)         (ws + 0);         // 3MB, after enc_bf dead
  float*          ghp      = (float*)         (ws + 3145728);   // 3MB
  unsigned short* wa1_bf   = (unsigned short*)(ws + 67108864);  // dead after scores
  float*          xp       = (float*)         (ws + 67108864);  // 2MB, after wa1_bf dead
  float*          part2    = (float*)         (ws + 69206016);
  float*          partials = (float*)         (ws + 69337088);  // dead after softmax
  float*          ctxp     = (float*)         (ws + 69337088);  // 2MB, after partials dead
  float*          attn     = (float*)         (ws + 71434240);
  unsigned short* ec_bf    = (unsigned short*)(ws + 71565312);
  unsigned short* hprev_bf = (unsigned short*)(ws + 71696384);
  unsigned short* x_bf     = (unsigned short*)(ws + 71761920);
  unsigned short* hr_bf    = (unsigned short*)(ws + 71827456);

  hipFuncSetAttribute((const void*)scores_gemm8,
                      hipFuncAttributeMaxDynamicSharedMemorySize, 131072);

  conv_f32_bf16<<<dim3(16384), dim3(256), 0, stream>>>(enc, enc_bf);
  wa1_prep_kernel<<<dim3(1024), dim3(256), 0, stream>>>(W_a1, hidden, b_a1, wa1_bf, part2);
  scores_gemm8<<<dim3(128, 4), dim3(512), 131072, stream>>>(enc_bf, wa1_bf, part2, W_a2, partials);
  softmax_kernel<<<dim3(32), dim3(1024), 0, stream>>>(partials, b_a2, attn);
  ctx_partial_kernel<<<dim3(16, 32), dim3(256), 0, stream>>>(enc_bf, attn, ctxp);
  prep_kernel<<<dim3(32), dim3(256), 0, stream>>>(ctxp, emb, word, hidden, ec_bf, hprev_bf);
  skinny_gemm<<<dim3(16, 16), dim3(256), 0, stream>>>(ec_bf, W_c, xp, (const float*)nullptr,
                                                      1024, 2048, 128, 0, 0);
  xfinish_kernel<<<dim3(128), dim3(256), 0, stream>>>(xp, b_c, x_bf);
  ihhh_gemm<<<dim3(48, 8, 2), dim3(256), 0, stream>>>(x_bf, hprev_bf, W_ih, W_hh, gip, ghp);
  gates_kernel<<<dim3(128), dim3(256), 0, stream>>>(gip, ghp, b_ih, b_hh, hidden,
                                                    out + (size_t)B_ * V_, hr_bf);
  skinny_gemm<<<dim3(786, 1), dim3(256), 0, stream>>>(hr_bf, W_fc, out, b_fc,
                                                      V_, 1024, 1024, V_, 1);
}